// Round 3
// baseline (175.417 us; speedup 1.0000x reference)
//
#include <hip/hip_runtime.h>
#include <hip/hip_bf16.h>
#include <cmath>

#define BATCH 4
#define SEQ 2048
#define DM 1024
#define NS 16
#define M_ROWS (BATCH * SEQ)

typedef short bf16x8 __attribute__((ext_vector_type(8)));
typedef short bf16x4 __attribute__((ext_vector_type(4)));
typedef float f32x4 __attribute__((ext_vector_type(4)));

// fp32 -> bf16 round-to-nearest-even
__device__ __forceinline__ short f2bf(float f) {
    union { float f; unsigned u; } a; a.f = f;
    unsigned u = a.u;
    return (short)((u + 0x7fffu + ((u >> 16) & 1u)) >> 16);
}
__device__ __forceinline__ float bf2f(unsigned short s) {
    union { unsigned u; float f; } a; a.u = ((unsigned)s) << 16;
    return a.f;
}

// ---------------------------------------------------------------------------
// Kernel 0: convert x, W1, W2, W3 fp32 -> bf16. Block-uniform segment select.
// Wcb = [W2(16 rows); W3(16 rows)], row-major, K contiguous.
// ---------------------------------------------------------------------------
__global__ void __launch_bounds__(256) convert_all(
    const float* __restrict__ x,  const float* __restrict__ W1,
    const float* __restrict__ W2, const float* __restrict__ W3,
    short* __restrict__ xb, short* __restrict__ W1b, short* __restrict__ Wcb)
{
    const int b = blockIdx.x;
    const int t = threadIdx.x;
    const float4* src; bf16x4* dst; int qbase;
    if (b < 2048)      { src = (const float4*)x;  dst = (bf16x4*)xb;  qbase = b * 1024; }
    else if (b < 2304) { src = (const float4*)W1; dst = (bf16x4*)W1b; qbase = (b - 2048) * 1024; }
    else if (b < 2308) { src = (const float4*)W2; dst = (bf16x4*)Wcb; qbase = (b - 2304) * 1024; }
    else               { src = (const float4*)W3; dst = (bf16x4*)(Wcb + NS * DM); qbase = (b - 2308) * 1024; }
    #pragma unroll
    for (int i = 0; i < 4; i++) {
        int q = qbase + i * 256 + t;
        float4 v = src[q];
        bf16x4 s;
        s.x = f2bf(v.x); s.y = f2bf(v.y); s.z = f2bf(v.z); s.w = f2bf(v.w);
        dst[q] = s;
    }
}

// ---------------------------------------------------------------------------
// Kernel 1: fused  z = xb @ W1b^T  (128x128 tile, NO LDS PIPELINE).
// Rounds 1-2 proved the global_load_lds⇄ds_read structure serializes every
// K-step (legalizer drains vmcnt before aliasing ds_reads; barriers lockstep
// 4 waves; 24-30KB unrolled body thrashes I$). All per-step data is L1/L2-hot
// (W1 XCD-slice 256KB, Wc 64KB resident; xb streamed once), so fragments are
// loaded DIRECTLY global->VGPR: per-lane base pointer + compile-time byte
// immediate (kk*128+ks*64 <= 1984), zero barriers / zero LDS ops in the loop,
// ~9KB body, compiler pipelines loads across MFMAs with precise vmcnt.
// Fragment addresses are the exact algebraic image of the old LDS swizzle:
// af[i] = xb[row][kk*64 + ks*32 + quad*8] -> numerics bit-identical.
// bc = sum_n (B+b2)(C+b3) in-loop; epilogue y = x * softplus(z+b1) * bc.
// ---------------------------------------------------------------------------
__global__ void __launch_bounds__(256, 2) gemm_fused(
    const short* __restrict__ xb, const short* __restrict__ W1b,
    const short* __restrict__ Wcb, const float* __restrict__ b1,
    const float* __restrict__ b2,  const float* __restrict__ b3,
    float* __restrict__ out)
{
    __shared__ float bcs[128];

    const int n0 = blockIdx.x * 128;
    const int m0 = blockIdx.y * 128;
    const int t = threadIdx.x;
    const int lane = t & 63;
    const int w = t >> 6;
    const int wm = (w >> 1) * 64;
    const int wn = (w & 1) * 64;
    const int lm = lane & 15;
    const int quad = lane >> 4;

    // per-lane fragment base pointers (loop-invariant; K-loop uses only
    // compile-time immediates on top of these)
    const short* pA[4]; const short* pB[4]; const short* pW[2];
    #pragma unroll
    for (int i = 0; i < 4; i++)
        pA[i] = xb + (size_t)(m0 + wm + i * 16 + lm) * DM + quad * 8;
    #pragma unroll
    for (int j = 0; j < 4; j++)
        pB[j] = W1b + (size_t)(n0 + wn + j * 16 + lm) * DM + quad * 8;
    #pragma unroll
    for (int h = 0; h < 2; h++)
        pW[h] = Wcb + (size_t)(h * 16 + lm) * DM + quad * 8;

    f32x4 acc[4][4] = {};    // main accumulators
    f32x4 abc[2][2] = {};    // bc: [i2][h] h=0:W2 h=1:W3

    #pragma unroll
    for (int kk = 0; kk < 16; kk++) {
        #pragma unroll
        for (int ks = 0; ks < 2; ks++) {
            const int eo = kk * 64 + ks * 32;   // element offset, compile-time
            bf16x8 af[4], bfv[4], wcv[2];
            #pragma unroll
            for (int i = 0; i < 4; i++)
                af[i] = *(const bf16x8*)(pA[i] + eo);
            #pragma unroll
            for (int j = 0; j < 4; j++)
                bfv[j] = *(const bf16x8*)(pB[j] + eo);
            #pragma unroll
            for (int h = 0; h < 2; h++)
                wcv[h] = *(const bf16x8*)(pW[h] + eo);

            #pragma unroll
            for (int i = 0; i < 4; i++)
                #pragma unroll
                for (int j = 0; j < 4; j++)
                    acc[i][j] = __builtin_amdgcn_mfma_f32_16x16x32_bf16(
                        af[i], bfv[j], acc[i][j], 0, 0, 0);

            // bc: the two waves with the same wm split its 64 rows.
            // WAVE-UNIFORM branch, constant indices (keeps af in VGPRs).
            if (w & 1) {
                #pragma unroll
                for (int h = 0; h < 2; h++) {
                    abc[0][h] = __builtin_amdgcn_mfma_f32_16x16x32_bf16(
                        af[2], wcv[h], abc[0][h], 0, 0, 0);
                    abc[1][h] = __builtin_amdgcn_mfma_f32_16x16x32_bf16(
                        af[3], wcv[h], abc[1][h], 0, 0, 0);
                }
            } else {
                #pragma unroll
                for (int h = 0; h < 2; h++) {
                    abc[0][h] = __builtin_amdgcn_mfma_f32_16x16x32_bf16(
                        af[0], wcv[h], abc[0][h], 0, 0, 0);
                    abc[1][h] = __builtin_amdgcn_mfma_f32_16x16x32_bf16(
                        af[1], wcv[h], abc[1][h], 0, 0, 0);
                }
            }
        }
    }

    // ---- bc reduce: abc[i2][h], n=lm, m-row = wm+(w&1)*32+i2*16+quad*4+r ----
    float bb2 = b2[lm], bb3 = b3[lm];
    #pragma unroll
    for (int i2 = 0; i2 < 2; i2++) {
        #pragma unroll
        for (int r = 0; r < 4; r++) {
            float p = (abc[i2][0][r] + bb2) * (abc[i2][1][r] + bb3);
            p += __shfl_xor(p, 1);
            p += __shfl_xor(p, 2);
            p += __shfl_xor(p, 4);
            p += __shfl_xor(p, 8);
            if (lm == 0) bcs[wm + (w & 1) * 32 + i2 * 16 + quad * 4 + r] = p;
        }
    }
    __syncthreads();

    // ---- epilogue: D col(n)=lm, row(m)=quad*4+r; fast stable softplus ----
    const unsigned short* xbu = (const unsigned short*)xb;
    float b1v[4];
    #pragma unroll
    for (int j = 0; j < 4; j++) b1v[j] = b1[n0 + wn + j * 16 + lm];

    #pragma unroll
    for (int i = 0; i < 4; i++) {
        #pragma unroll
        for (int r = 0; r < 4; r++) {
            int lrow = wm + i * 16 + quad * 4 + r;
            int gm = m0 + lrow;
            float bcv = bcs[lrow];
            const unsigned short* xrow = xbu + (size_t)gm * DM + n0 + wn + lm;
            float* orow = out + (size_t)gm * DM + n0 + wn + lm;
            #pragma unroll
            for (int j = 0; j < 4; j++) {
                float z = acc[i][j][r] + b1v[j];
                float az = __builtin_fabsf(z);
                float sp = fmaxf(z, 0.f) + __logf(1.f + __expf(-az));
                orow[j * 16] = bf2f(xrow[j * 16]) * sp * bcv;
            }
        }
    }
}

extern "C" void kernel_launch(void* const* d_in, const int* in_sizes, int n_in,
                              void* d_out, int out_size, void* d_ws, size_t ws_size,
                              hipStream_t stream) {
    const float* x  = (const float*)d_in[0];
    const float* W1 = (const float*)d_in[1];
    const float* b1 = (const float*)d_in[2];
    const float* W2 = (const float*)d_in[3];
    const float* b2 = (const float*)d_in[4];
    const float* W3 = (const float*)d_in[5];
    const float* b3 = (const float*)d_in[6];
    // d_in[7] = A is dead math
    float* out = (float*)d_out;

    // ws: xb 16 MiB @0 | W1b 2 MiB @16M | Wcb 64 KiB @18M
    char* ws = (char*)d_ws;
    short* xb  = (short*)(ws);
    short* W1b = (short*)(ws + (size_t)16 * 1024 * 1024);
    short* Wcb = (short*)(ws + (size_t)18 * 1024 * 1024);

    convert_all<<<2312, 256, 0, stream>>>(x, W1, W2, W3, xb, W1b, Wcb);

    // grid (8,64): linear id % 8 == n-block -> each XCD sees one W1b slice
    dim3 grid(DM / 128, M_ROWS / 128);
    gemm_fused<<<grid, 256, 0, stream>>>(xb, W1b, Wcb, b1, b2, b3, out);
}